// Round 4
// baseline (38.089 us; speedup 1.0000x reference)
//
#include <hip/hip_runtime.h>

#define NN 8192
#define BB 1024
#define KK 8
#define CC 10
#define NT 512
#define CHUNK (NN/NT)   // 16
#define NW (NT/64)      // 8 waves

__global__ void pack_kernel(const int* __restrict__ c_in, const int* __restrict__ delta_in,
                            unsigned* __restrict__ pairs, unsigned* __restrict__ dmask_g) {
    int n = blockIdx.x * blockDim.x + threadIdx.x;
    if (n >= NN) return;
    const int4* p = reinterpret_cast<const int4*>(c_in + (size_t)n * KK);
    int4 lo = p[0], hi = p[1];
    unsigned p0 = (unsigned)(lo.x * 10 + lo.y);   // pair index 0..99
    unsigned p1 = (unsigned)(lo.z * 10 + lo.w);
    unsigned p2 = (unsigned)(hi.x * 10 + hi.y);
    unsigned p3 = (unsigned)(hi.z * 10 + hi.w);
    pairs[n] = p0 | (p1 << 7) | (p2 << 14) | (p3 << 21);
    // delta bitmask: word w covers n in [32w, 32w+32)
    unsigned long long bal = __ballot(delta_in[n] & 1);
    if ((threadIdx.x & 63) == 0) {
        dmask_g[n >> 5]       = (unsigned)(bal & 0xffffffffull);
        dmask_g[(n >> 5) + 1] = (unsigned)(bal >> 32);
    }
}

// exclusive block scan of v over NT threads; also returns the block total.
// ws must be a fresh float[NW] slot per call.
__device__ __forceinline__ float block_excl_scan(float v, int lane, int wv, float* ws,
                                                 float* total) {
    float x = v;
    #pragma unroll
    for (int d = 1; d < 64; d <<= 1) {
        float y = __shfl_up(x, d);
        if (lane >= d) x += y;
    }
    if (lane == 63) ws[wv] = x;
    __syncthreads();
    float off = x - v, tot = 0.0f;
    #pragma unroll
    for (int w = 0; w < NW; w++) {
        float y = ws[w];              // broadcast reads, conflict-free
        tot += y;
        if (w < wv) off += y;
    }
    *total = tot;
    return off;
}

__global__ __launch_bounds__(NT, 8) void beran_kernel(
    const float* __restrict__ c_p, const float* __restrict__ bandwidth,
    const int* __restrict__ c_in, const int* __restrict__ delta_in,
    const unsigned* __restrict__ pairs, const unsigned* __restrict__ dmask_g,
    float* __restrict__ out)
{
    __shared__ float ttab[KK * CC];     // single-concept table
    __shared__ float ttab2[4 * 100];    // pair table: ttab2[k*100 + c0*10+c1]
    __shared__ float Apart[KK];
    __shared__ float wsB[NW];
    __shared__ float wsC[NW];

    const int b    = blockIdx.x;
    const int t    = threadIdx.x;
    const int lane = t & 63;
    const int wv   = t >> 6;
    const int base = t * CHUNK;

    // ---- softmax + metric table t[k][c] = invbw - 2*p*invbw ; A = sum p^2*invbw ----
    if (t < KK) {
        const int k = t;
        float v[CC];
        float mx = -1e30f;
        #pragma unroll
        for (int c = 0; c < CC; c++) { v[c] = c_p[((size_t)b*KK + k)*CC + c]; mx = fmaxf(mx, v[c]); }
        float se = 0.0f;
        #pragma unroll
        for (int c = 0; c < CC; c++) { v[c] = __expf(v[c] - mx); se += v[c]; }
        float inv = 1.0f / se;
        float Ak = 0.0f;
        #pragma unroll
        for (int c = 0; c < CC; c++) {
            float p  = v[c] * inv;
            float bw = bandwidth[k*CC + c];
            bw = fminf(fmaxf(bw, 0.001f), 10.0f);
            float ib = 1.0f / bw;
            ttab[k*CC + c] = ib - 2.0f * p * ib;
            Ak += p * p * ib;
        }
        Apart[k] = Ak;
    }
    __syncthreads();
    if (t < 400) {
        int k = t / 100, p = t % 100;
        ttab2[t] = ttab[(k*2)*CC + p/10] + ttab[(k*2+1)*CC + p%10];
    }
    float A = 0.0f;
    #pragma unroll
    for (int k = 0; k < KK; k++) A += Apart[k];   // broadcast reads
    __syncthreads();

    // ---- pass A (chunked, register-resident): raw weight cumsum ----
    float creg[CHUNK];
    unsigned dm = 0;
    float run = 0.0f;
    if (pairs) {
        {
            unsigned dm32 = dmask_g[t >> 1];
            dm = (dm32 >> ((t & 1) * 16)) & 0xffffu;
        }
        #pragma unroll
        for (int g = 0; g < CHUNK / 4; g++) {
            uint4 pk = *reinterpret_cast<const uint4*>(pairs + base + g * 4);
#define DOPAIR(pw, idx) { \
            float m = A + ttab2[(pw) & 127] + ttab2[100 + (((pw) >> 7) & 127)] \
                    + ttab2[200 + (((pw) >> 14) & 127)] + ttab2[300 + ((pw) >> 21)]; \
            run += __expf(-m); creg[idx] = run; }
            DOPAIR(pk.x, g*4 + 0)
            DOPAIR(pk.y, g*4 + 1)
            DOPAIR(pk.z, g*4 + 2)
            DOPAIR(pk.w, g*4 + 3)
#undef DOPAIR
        }
    } else {
        #pragma unroll
        for (int i = 0; i < CHUNK; i++) {
            const int4* p4 = reinterpret_cast<const int4*>(c_in + (size_t)(base + i) * KK);
            int4 lo4 = p4[0], hi4 = p4[1];
            float m = A;
            m += ttab[0*CC + lo4.x] + ttab[1*CC + lo4.y] + ttab[2*CC + lo4.z] + ttab[3*CC + lo4.w];
            m += ttab[4*CC + hi4.x] + ttab[5*CC + hi4.y] + ttab[6*CC + hi4.z] + ttab[7*CC + hi4.w];
            run += __expf(-m);
            creg[i] = run;
            dm |= (unsigned)(delta_in[base + i] & 1) << i;
        }
    }

    // ---- scan 1: block-exclusive offset + total weight sum ----
    float s;
    const float off_raw = block_excl_scan(run, lane, wv, wsB, &s);
    const float invs = (s < 1e-13f) ? 0.0f : 1.0f / s;

    // ---- pass C (registers): xi + hazard cumsum, one log per element ----
    const float ISO = 1.00001e-5f;   // atol + rtol*|1|
    float csprev = off_raw * invs;   // t==0 -> 0
    float Lprev  = __logf(1.0f - csprev);
    float run2 = 0.0f;
    #pragma unroll
    for (int i = 0; i < CHUNK; i++) {
        float cs = (creg[i] + off_raw) * invs;
        float L  = __logf(1.0f - cs);
        bool bad = (fabsf(csprev - 1.0f) <= ISO) || (fabsf(cs - 1.0f) <= ISO);
        float xi = bad ? 0.0f : (Lprev - L);
        float f  = ((dm >> i) & 1u) ? xi : 0.0f;
        run2 += f;
        creg[i] = run2;
        csprev = cs;
        Lprev  = L;
    }

    // ---- scan 2: hazard offsets + total hazard ----
    float H;
    const float off2 = block_excl_scan(run2, lane, wv, wsC, &H);

    // ---- epilogue (registers -> global): surv_func and normalized steps ----
    const float ss = 1.0f - __expf(-H);              // telescoped step sum
    const float invss = (ss < 1e-13f) ? 0.0f : 1.0f / ss;
    float sprev = (t == 0) ? 1.0f : __expf(-off2);   // surv[base-1]
    float* outS = out + (size_t)b * NN + base;
    float* outT = out + (size_t)BB * NN + (size_t)b * NN + base;
    #pragma unroll
    for (int g = 0; g < CHUNK / 4; g++) {
        float s0 = __expf(-(creg[g*4 + 0] + off2));
        float s1 = __expf(-(creg[g*4 + 1] + off2));
        float s2 = __expf(-(creg[g*4 + 2] + off2));
        float s3 = __expf(-(creg[g*4 + 3] + off2));
        *reinterpret_cast<float4*>(outS + g*4) = make_float4(s0, s1, s2, s3);
        *reinterpret_cast<float4*>(outT + g*4) =
            make_float4((sprev - s0) * invss, (s0 - s1) * invss,
                        (s1 - s2) * invss, (s2 - s3) * invss);
        sprev = s3;
    }
}

extern "C" void kernel_launch(void* const* d_in, const int* in_sizes, int n_in,
                              void* d_out, int out_size, void* d_ws, size_t ws_size,
                              hipStream_t stream) {
    const float* c_p       = (const float*)d_in[0];
    const float* bandwidth = (const float*)d_in[1];
    const int*   c_in      = (const int*)d_in[2];
    const int*   delta_in  = (const int*)d_in[3];
    float* out = (float*)d_out;

    unsigned* pairs   = nullptr;
    unsigned* dmask_g = nullptr;
    const size_t need = (size_t)NN * sizeof(unsigned) + (size_t)(NN / 32) * sizeof(unsigned);
    if (ws_size >= need) {
        pairs   = (unsigned*)d_ws;
        dmask_g = (unsigned*)((char*)d_ws + (size_t)NN * sizeof(unsigned));
        pack_kernel<<<NN / 256, 256, 0, stream>>>(c_in, delta_in, pairs, dmask_g);
    }
    beran_kernel<<<BB, NT, 0, stream>>>(c_p, bandwidth, c_in, delta_in, pairs, dmask_g, out);
}

// Round 5
// 28.954 us; speedup vs baseline: 1.3155x; 1.3155x over previous
//
#include <hip/hip_runtime.h>

#define NN 8192
#define BB 1024
#define KK 8
#define CC 10
#define NT 512
#define CHUNK (NN/NT)   // 16
#define NW (NT/64)      // 8 waves

// LDS row-buffer swizzle: rotate column by row index -> both chunked and
// strided access patterns stay <=2-way per bank (free, per m136).
__device__ __forceinline__ int swz(int n) {
    return (n & ~31) | ((n + (n >> 5)) & 31);
}

__global__ void pack_kernel(const int* __restrict__ c_in, const int* __restrict__ delta_in,
                            unsigned* __restrict__ pairs, unsigned* __restrict__ dmask_g) {
    int n = blockIdx.x * blockDim.x + threadIdx.x;
    if (n >= NN) return;
    const int4* p = reinterpret_cast<const int4*>(c_in + (size_t)n * KK);
    int4 lo = p[0], hi = p[1];
    unsigned p0 = (unsigned)(lo.x * 10 + lo.y);   // pair index 0..99
    unsigned p1 = (unsigned)(lo.z * 10 + lo.w);
    unsigned p2 = (unsigned)(hi.x * 10 + hi.y);
    unsigned p3 = (unsigned)(hi.z * 10 + hi.w);
    pairs[n] = p0 | (p1 << 7) | (p2 << 14) | (p3 << 21);
    // delta bitmask: word w covers n in [32w, 32w+32)
    unsigned long long bal = __ballot(delta_in[n] & 1);
    if ((threadIdx.x & 63) == 0) {
        dmask_g[n >> 5]       = (unsigned)(bal & 0xffffffffull);
        dmask_g[(n >> 5) + 1] = (unsigned)(bal >> 32);
    }
}

// exclusive block scan of v over NT threads; also returns the block total.
// ws must be a fresh float[NW] slot per call.
__device__ __forceinline__ float block_excl_scan(float v, int lane, int wv, float* ws,
                                                 float* total) {
    float x = v;
    #pragma unroll
    for (int d = 1; d < 64; d <<= 1) {
        float y = __shfl_up(x, d);
        if (lane >= d) x += y;
    }
    if (lane == 63) ws[wv] = x;
    __syncthreads();
    float off = x - v, tot = 0.0f;
    #pragma unroll
    for (int w = 0; w < NW; w++) {
        float y = ws[w];              // broadcast reads, conflict-free
        tot += y;
        if (w < wv) off += y;
    }
    *total = tot;
    return off;
}

__global__ __launch_bounds__(NT, 8) void beran_kernel(
    const float* __restrict__ c_p, const float* __restrict__ bandwidth,
    const int* __restrict__ c_in, const int* __restrict__ delta_in,
    const unsigned* __restrict__ pairs, const unsigned* __restrict__ dmask_g,
    float* __restrict__ out)
{
    __shared__ float a[NN];             // 32 KB swizzled surv buffer (epilogue transpose)
    __shared__ float ttab[KK * CC];     // single-concept table
    __shared__ float ttab2[4 * 100];    // pair table: ttab2[k*100 + c0*10+c1]
    __shared__ float Apart[KK];
    __shared__ float wsB[NW];
    __shared__ float wsC[NW];

    const int b    = blockIdx.x;
    const int t    = threadIdx.x;
    const int lane = t & 63;
    const int wv   = t >> 6;
    const int base = t * CHUNK;

    // ---- softmax + metric table t[k][c] = invbw - 2*p*invbw ; A = sum p^2*invbw ----
    if (t < KK) {
        const int k = t;
        float v[CC];
        float mx = -1e30f;
        #pragma unroll
        for (int c = 0; c < CC; c++) { v[c] = c_p[((size_t)b*KK + k)*CC + c]; mx = fmaxf(mx, v[c]); }
        float se = 0.0f;
        #pragma unroll
        for (int c = 0; c < CC; c++) { v[c] = __expf(v[c] - mx); se += v[c]; }
        float inv = 1.0f / se;
        float Ak = 0.0f;
        #pragma unroll
        for (int c = 0; c < CC; c++) {
            float p  = v[c] * inv;
            float bw = bandwidth[k*CC + c];
            bw = fminf(fmaxf(bw, 0.001f), 10.0f);
            float ib = 1.0f / bw;
            ttab[k*CC + c] = ib - 2.0f * p * ib;
            Ak += p * p * ib;
        }
        Apart[k] = Ak;
    }
    __syncthreads();
    if (t < 400) {
        int k = t / 100, p = t % 100;
        ttab2[t] = ttab[(k*2)*CC + p/10] + ttab[(k*2+1)*CC + p%10];
    }
    float A = 0.0f;
    #pragma unroll
    for (int k = 0; k < KK; k++) A += Apart[k];   // broadcast reads
    __syncthreads();

    // ---- pass A (chunked, register-resident): raw weight cumsum ----
    float creg[CHUNK];
    unsigned dm = 0;
    float run = 0.0f;
    if (pairs) {
        {
            unsigned dm32 = dmask_g[t >> 1];
            dm = (dm32 >> ((t & 1) * 16)) & 0xffffu;
        }
        #pragma unroll
        for (int g = 0; g < CHUNK / 4; g++) {
            uint4 pk = *reinterpret_cast<const uint4*>(pairs + base + g * 4);
#define DOPAIR(pw, idx) { \
            float m = A + ttab2[(pw) & 127] + ttab2[100 + (((pw) >> 7) & 127)] \
                    + ttab2[200 + (((pw) >> 14) & 127)] + ttab2[300 + ((pw) >> 21)]; \
            run += __expf(-m); creg[idx] = run; }
            DOPAIR(pk.x, g*4 + 0)
            DOPAIR(pk.y, g*4 + 1)
            DOPAIR(pk.z, g*4 + 2)
            DOPAIR(pk.w, g*4 + 3)
#undef DOPAIR
        }
    } else {
        #pragma unroll
        for (int i = 0; i < CHUNK; i++) {
            const int4* p4 = reinterpret_cast<const int4*>(c_in + (size_t)(base + i) * KK);
            int4 lo4 = p4[0], hi4 = p4[1];
            float m = A;
            m += ttab[0*CC + lo4.x] + ttab[1*CC + lo4.y] + ttab[2*CC + lo4.z] + ttab[3*CC + lo4.w];
            m += ttab[4*CC + hi4.x] + ttab[5*CC + hi4.y] + ttab[6*CC + hi4.z] + ttab[7*CC + hi4.w];
            run += __expf(-m);
            creg[i] = run;
            dm |= (unsigned)(delta_in[base + i] & 1) << i;
        }
    }

    // ---- scan 1: block-exclusive offset + total weight sum ----
    float s;
    const float off_raw = block_excl_scan(run, lane, wv, wsB, &s);
    const float invs = (s < 1e-13f) ? 0.0f : 1.0f / s;

    // ---- pass C (registers): xi + hazard cumsum, one log per element ----
    const float ISO = 1.00001e-5f;   // atol + rtol*|1|
    float csprev = off_raw * invs;   // t==0 -> 0
    float Lprev  = __logf(1.0f - csprev);
    float run2 = 0.0f;
    #pragma unroll
    for (int i = 0; i < CHUNK; i++) {
        float cs = (creg[i] + off_raw) * invs;
        float L  = __logf(1.0f - cs);
        bool bad = (fabsf(csprev - 1.0f) <= ISO) || (fabsf(cs - 1.0f) <= ISO);
        float xi = bad ? 0.0f : (Lprev - L);
        float f  = ((dm >> i) & 1u) ? xi : 0.0f;
        run2 += f;
        creg[i] = run2;
        csprev = cs;
        Lprev  = L;
    }

    // ---- scan 2: hazard offsets ----
    float H;
    const float off2 = block_excl_scan(run2, lane, wv, wsC, &H);

    // ---- pass D (chunked write): surv_func into swizzled LDS ----
    #pragma unroll
    for (int i = 0; i < CHUNK; i++) a[swz(base + i)] = __expf(-(creg[i] + off2));
    __syncthreads();

    // ---- pass E (strided float4): coalesced write of surv_func and steps ----
    const float surv_last = a[swz(NN - 1)];          // broadcast
    const float ss = 1.0f - surv_last;               // telescoped step sum
    const float invss = (ss < 1e-13f) ? 0.0f : 1.0f / ss;
    float* outS = out + (size_t)b * NN;
    float* outT = out + (size_t)BB * NN + (size_t)b * NN;
    #pragma unroll
    for (int j = 0; j < NN / (NT * 4); j++) {        // 4 iterations
        int n0 = j * NT * 4 + t * 4;
        float s0 = a[swz(n0)];
        float s1 = a[swz(n0 + 1)];
        float s2 = a[swz(n0 + 2)];
        float s3 = a[swz(n0 + 3)];
        float sp = (n0 == 0) ? 1.0f : a[swz(n0 - 1)];
        *reinterpret_cast<float4*>(outS + n0) = make_float4(s0, s1, s2, s3);
        *reinterpret_cast<float4*>(outT + n0) =
            make_float4((sp - s0) * invss, (s0 - s1) * invss,
                        (s1 - s2) * invss, (s2 - s3) * invss);
    }
}

extern "C" void kernel_launch(void* const* d_in, const int* in_sizes, int n_in,
                              void* d_out, int out_size, void* d_ws, size_t ws_size,
                              hipStream_t stream) {
    const float* c_p       = (const float*)d_in[0];
    const float* bandwidth = (const float*)d_in[1];
    const int*   c_in      = (const int*)d_in[2];
    const int*   delta_in  = (const int*)d_in[3];
    float* out = (float*)d_out;

    unsigned* pairs   = nullptr;
    unsigned* dmask_g = nullptr;
    const size_t need = (size_t)NN * sizeof(unsigned) + (size_t)(NN / 32) * sizeof(unsigned);
    if (ws_size >= need) {
        pairs   = (unsigned*)d_ws;
        dmask_g = (unsigned*)((char*)d_ws + (size_t)NN * sizeof(unsigned));
        pack_kernel<<<NN / 256, 256, 0, stream>>>(c_in, delta_in, pairs, dmask_g);
    }
    beran_kernel<<<BB, NT, 0, stream>>>(c_p, bandwidth, c_in, delta_in, pairs, dmask_g, out);
}